// Round 2
// baseline (1061.279 us; speedup 1.0000x reference)
//
#include <hip/hip_runtime.h>
#include <hip/hip_bf16.h>
#include <math.h>

#define BB 64
#define NN 256
#define D_VIS 2048
#define D_LBL 512
#define HH 8
#define FF 256
#define DG 2048   // D_GAT = H*F
#define DE 512    // D_EMB
#define ALPHA 0.2f
#define ITILE 16
#define NEG_BIG -1.0e30f

using bf16 = __hip_bfloat16;
__device__ __forceinline__ float b2f(bf16 x) { return __bfloat162float(x); }

// ---------------- K1: WhL = labels (256x512) @ Wg[0:512,:] -> (256,2048) fp32
__global__ void __launch_bounds__(256) k_whl(const float* __restrict__ labels,
                                             const float* __restrict__ Wg,
                                             float* __restrict__ WhL) {
    __shared__ float x[4][D_LBL];
    const int t = threadIdx.x;
    const int n0 = blockIdx.x * 4;
    for (int r = 0; r < 4; ++r)
        for (int d = t; d < D_LBL; d += 256)
            x[r][d] = labels[(n0 + r) * D_LBL + d];
    __syncthreads();
    float acc[4][8];
#pragma unroll
    for (int r = 0; r < 4; ++r)
#pragma unroll
        for (int k = 0; k < 8; ++k) acc[r][k] = 0.f;
    for (int d = 0; d < D_LBL; ++d) {
        const float* wr = Wg + (size_t)d * DG;
        float w[8];
#pragma unroll
        for (int k = 0; k < 8; ++k) w[k] = wr[t + 256 * k];
#pragma unroll
        for (int r = 0; r < 4; ++r) {
            const float xv = x[r][d];
#pragma unroll
            for (int k = 0; k < 8; ++k) acc[r][k] = fmaf(xv, w[k], acc[r][k]);
        }
    }
    for (int r = 0; r < 4; ++r)
#pragma unroll
        for (int k = 0; k < 8; ++k)
            WhL[(size_t)(n0 + r) * DG + t + 256 * k] = acc[r][k];
}

// ---------------- K2: WhV = visual (64x2048) @ Wg[512:2560,:] -> (64,2048) fp32
__global__ void __launch_bounds__(256) k_whv(const float* __restrict__ visual,
                                             const float* __restrict__ Wg,
                                             float* __restrict__ WhV) {
    __shared__ float x[4][D_VIS]; // 32 KB
    const int t = threadIdx.x;
    const int b0 = blockIdx.x * 4;
    for (int r = 0; r < 4; ++r)
        for (int d = t; d < D_VIS; d += 256)
            x[r][d] = visual[(b0 + r) * D_VIS + d];
    __syncthreads();
    float acc[4][8];
#pragma unroll
    for (int r = 0; r < 4; ++r)
#pragma unroll
        for (int k = 0; k < 8; ++k) acc[r][k] = 0.f;
    for (int d = 0; d < D_VIS; ++d) {
        const float* wr = Wg + (size_t)(D_LBL + d) * DG;
        float w[8];
#pragma unroll
        for (int k = 0; k < 8; ++k) w[k] = wr[t + 256 * k];
#pragma unroll
        for (int r = 0; r < 4; ++r) {
            const float xv = x[r][d];
#pragma unroll
            for (int k = 0; k < 8; ++k) acc[r][k] = fmaf(xv, w[k], acc[r][k]);
        }
    }
    for (int r = 0; r < 4; ++r)
#pragma unroll
        for (int k = 0; k < 8; ++k)
            WhV[(size_t)(b0 + r) * DG + t + 256 * k] = acc[r][k];
}

// ---------------- K3: per-row head projections  src[n,h] = sum_f M[n,h*F+f]*a_src[h,f]
__global__ void k_proj(const float* __restrict__ M,
                       const float* __restrict__ a_src, const float* __restrict__ a_dst,
                       float* __restrict__ src, float* __restrict__ dst) {
    const int n = blockIdx.x;
    const int lane = threadIdx.x; // block = 64 (one wave)
    const float* mr = M + (size_t)n * DG;
    for (int h = 0; h < HH; ++h) {
        float s = 0.f, d_ = 0.f;
#pragma unroll
        for (int k = 0; k < 4; ++k) {
            const int f = lane + 64 * k;
            const float v = mr[h * FF + f];
            s  = fmaf(v, a_src[h * FF + f], s);
            d_ = fmaf(v, a_dst[h * FF + f], d_);
        }
#pragma unroll
        for (int off = 32; off; off >>= 1) {
            s  += __shfl_down(s, off);
            d_ += __shfl_down(d_, off);
        }
        if (lane == 0) { src[n * HH + h] = s; dst[n * HH + h] = d_; }
    }
}

// ---------------- K4: fused attention: softmax(mask(leaky(e))) @ WhL + WhV, ELU, -> bf16 out
// grid = B*H*16 blocks; block (b,h,it) computes out rows [it*16, it*16+16) for head h.
__global__ void __launch_bounds__(256) k_gat(const float* __restrict__ WhL,
                                             const float* __restrict__ WhV,
                                             const float* __restrict__ srcL,
                                             const float* __restrict__ dstL,
                                             const float* __restrict__ srcV,
                                             const float* __restrict__ dstV,
                                             const float* __restrict__ adj,
                                             bf16* __restrict__ outb) {
    const int bid = blockIdx.x;
    const int it = bid & 15;
    const int h  = (bid >> 4) & 7;
    const int b  = bid >> 7;
    const int i0 = it * ITILE;
    const int t = threadIdx.x;

    __shared__ __align__(16) float Pt[NN][ITILE + 4]; // [j][i], row = 80 B (16B-aligned)
    __shared__ float sl[ITILE];
    __shared__ float dl[NN];

    if (t < ITILE) sl[t] = srcL[(i0 + t) * HH + h];
    dl[t] = dstL[t * HH + h];
    const float c = srcV[b * HH + h] + dstV[b * HH + h];
    __syncthreads();

    // ---- phase 1: build P rows (16 rows, 16 threads per row)
    const int row = t >> 4;   // 0..15
    const int sub = t & 15;   // 0..15
    const int i = i0 + row;
    float sc[16];
    float m = NEG_BIG;
#pragma unroll
    for (int jj = 0; jj < 16; ++jj) {
        const int j = sub + 16 * jj;
        float e = c + sl[row] + dl[j];
        e = e > 0.f ? e : ALPHA * e;
        const bool valid = adj[i * NN + j] > 0.f;
        const float s = valid ? e : NEG_BIG;
        sc[jj] = s;
        m = fmaxf(m, s);
    }
#pragma unroll
    for (int off = 1; off < 16; off <<= 1) m = fmaxf(m, __shfl_xor(m, off));
    float sum = 0.f;
#pragma unroll
    for (int jj = 0; jj < 16; ++jj) {
        const float p = __expf(sc[jj] - m); // masked -> exp(-1e30) = 0
        sc[jj] = p;
        sum += p;
    }
#pragma unroll
    for (int off = 1; off < 16; off <<= 1) sum += __shfl_xor(sum, off);
    const float inv = 1.0f / sum;
#pragma unroll
    for (int jj = 0; jj < 16; ++jj) {
        const int j = sub + 16 * jj;
        Pt[j][row] = sc[jj] * inv;
    }
    __syncthreads();

    // ---- phase 2: out[i, f] = sum_j Pt[j][i] * WhL[j, h*F+f]   (fp32 vector FMA)
    const int fi = t & 63;   // f = 4*fi .. 4*fi+3
    const int ig = t >> 6;   // i-in-tile = 4*ig .. 4*ig+3
    const float* wbase = WhL + h * FF + 4 * fi;
    float acc[4][4];
#pragma unroll
    for (int a = 0; a < 4; ++a)
#pragma unroll
        for (int k = 0; k < 4; ++k) acc[a][k] = 0.f;
    for (int j = 0; j < NN; ++j) {
        const float4 w = *(const float4*)(wbase + (size_t)j * DG);
        const float4 p = *(const float4*)(&Pt[j][4 * ig]); // wave-uniform -> LDS broadcast
        float pa[4] = {p.x, p.y, p.z, p.w};
        float wa[4] = {w.x, w.y, w.z, w.w};
#pragma unroll
        for (int a = 0; a < 4; ++a)
#pragma unroll
            for (int k = 0; k < 4; ++k) acc[a][k] = fmaf(pa[a], wa[k], acc[a][k]);
    }
    const float4 wv = *(const float4*)(WhV + (size_t)b * DG + h * FF + 4 * fi);
    const float wva[4] = {wv.x, wv.y, wv.z, wv.w};
#pragma unroll
    for (int a = 0; a < 4; ++a) {
        const int gi = i0 + 4 * ig + a;
        bf16 pk[4];
#pragma unroll
        for (int k = 0; k < 4; ++k) {
            float x = acc[a][k] + wva[k];
            x = x > 0.f ? x : (expf(x) - 1.0f); // ELU
            pk[k] = __float2bfloat16(x);
        }
        __builtin_memcpy(outb + ((size_t)(b * NN + gi)) * DG + h * FF + 4 * fi, pk, 8);
    }
}

// ---------------- K5: pooling scores s[b,n] = <out[b,n,:], pool_q>
__global__ void __launch_bounds__(256) k_pscore(const bf16* __restrict__ outb,
                                                const float* __restrict__ pool_q,
                                                float* __restrict__ ps) {
    const int bn = blockIdx.x;
    const bf16* rowp = outb + (size_t)bn * DG;
    const int t = threadIdx.x;
    float s = 0.f;
#pragma unroll
    for (int k = 0; k < 8; ++k) {
        const int d = t + 256 * k;
        s = fmaf(b2f(rowp[d]), pool_q[d], s);
    }
    __shared__ float red[4];
#pragma unroll
    for (int off = 32; off; off >>= 1) s += __shfl_down(s, off);
    if ((t & 63) == 0) red[t >> 6] = s;
    __syncthreads();
    if (t == 0) ps[bn] = red[0] + red[1] + red[2] + red[3];
}

// ---------------- K5b: softmax over n (in place), block per b, 256 threads (one n each)
__global__ void __launch_bounds__(256) k_psoftmax(float* __restrict__ ps) {
    const int b = blockIdx.x, t = threadIdx.x;
    const float v = ps[b * NN + t];
    __shared__ float redm[4];
    __shared__ float reds[4];
    float m = v;
#pragma unroll
    for (int off = 32; off; off >>= 1) m = fmaxf(m, __shfl_xor(m, off));
    if ((t & 63) == 0) redm[t >> 6] = m;
    __syncthreads();
    m = fmaxf(fmaxf(redm[0], redm[1]), fmaxf(redm[2], redm[3]));
    const float e = expf(v - m);
    float s = e;
#pragma unroll
    for (int off = 32; off; off >>= 1) s += __shfl_xor(s, off);
    if ((t & 63) == 0) reds[t >> 6] = s;
    __syncthreads();
    s = reds[0] + reds[1] + reds[2] + reds[3];
    ps[b * NN + t] = e / s;
}

// ---------------- K6: pooled[b,:] = sum_n pw[b,n] * out[b,n,:]
__global__ void __launch_bounds__(256) k_pool(const bf16* __restrict__ outb,
                                              const float* __restrict__ pw,
                                              float* __restrict__ pooled) {
    const int b = blockIdx.x, t = threadIdx.x;
    __shared__ float w[NN];
    w[t] = pw[b * NN + t];
    __syncthreads();
    float acc[8];
#pragma unroll
    for (int k = 0; k < 8; ++k) acc[k] = 0.f;
    const bf16* base = outb + (size_t)b * NN * DG;
    for (int n = 0; n < NN; ++n) {
        const float wn = w[n];
        const bf16* rowp = base + (size_t)n * DG;
#pragma unroll
        for (int k = 0; k < 8; ++k) acc[k] = fmaf(wn, b2f(rowp[t + 256 * k]), acc[k]);
    }
#pragma unroll
    for (int k = 0; k < 8; ++k) pooled[(size_t)b * DG + t + 256 * k] = acc[k];
}

// ---------------- K7: final = pooled (64x2048) @ fc_W (2048x512) + fc_b -> fp32 out
__global__ void __launch_bounds__(256) k_fc(const float* __restrict__ pooled,
                                            const float* __restrict__ fcW,
                                            const float* __restrict__ fcb,
                                            float* __restrict__ out) {
    const int b = blockIdx.x, t = threadIdx.x;
    __shared__ float x[DG];
    for (int d = t; d < DG; d += 256) x[d] = pooled[(size_t)b * DG + d];
    __syncthreads();
    float a0 = 0.f, a1 = 0.f;
    for (int d = 0; d < DG; ++d) {
        const float xv = x[d];
        a0 = fmaf(xv, fcW[d * DE + t], a0);
        a1 = fmaf(xv, fcW[d * DE + t + 256], a1);
    }
    out[b * DE + t]       = a0 + fcb[t];
    out[b * DE + t + 256] = a1 + fcb[t + 256];
}

extern "C" void kernel_launch(void* const* d_in, const int* in_sizes, int n_in,
                              void* d_out, int out_size, void* d_ws, size_t ws_size,
                              hipStream_t stream) {
    (void)in_sizes; (void)n_in; (void)out_size; (void)ws_size;
    const float* visual = (const float*)d_in[0];
    const float* labels = (const float*)d_in[1];
    const float* adj    = (const float*)d_in[2];
    const float* Wg     = (const float*)d_in[3];
    const float* a_src  = (const float*)d_in[4];
    const float* a_dst  = (const float*)d_in[5];
    const float* pool_q = (const float*)d_in[6];
    const float* fcW    = (const float*)d_in[7];
    const float* fcb    = (const float*)d_in[8];
    float* out = (float*)d_out;

    // workspace layout (fp32 region then bf16 out staging); total ~70.3 MB
    float* ws_f   = (float*)d_ws;
    float* WhL    = ws_f;                  // 256*2048
    float* WhV    = WhL + NN * DG;         // 64*2048
    float* srcL   = WhV + BB * DG;         // 256*8
    float* dstL   = srcL + NN * HH;        // 256*8
    float* srcV   = dstL + NN * HH;        // 64*8
    float* dstV   = srcV + BB * HH;        // 64*8
    float* ps     = dstV + BB * HH;        // 64*256
    float* pooled = ps + BB * NN;          // 64*2048
    bf16*  outb   = (bf16*)(pooled + BB * DG); // 64*256*2048 bf16

    k_whl<<<NN / 4, 256, 0, stream>>>(labels, Wg, WhL);
    k_whv<<<BB / 4, 256, 0, stream>>>(visual, Wg, WhV);
    k_proj<<<NN, 64, 0, stream>>>(WhL, a_src, a_dst, srcL, dstL);
    k_proj<<<BB, 64, 0, stream>>>(WhV, a_src, a_dst, srcV, dstV);
    k_gat<<<BB * HH * 16, 256, 0, stream>>>(WhL, WhV, srcL, dstL, srcV, dstV, adj, outb);
    k_pscore<<<BB * NN, 256, 0, stream>>>(outb, pool_q, ps);
    k_psoftmax<<<BB, 256, 0, stream>>>(ps);
    k_pool<<<BB, 256, 0, stream>>>(outb, ps, pooled);
    k_fc<<<BB, 256, 0, stream>>>(pooled, fcW, fcb, out);
}

// Round 3
// 564.226 us; speedup vs baseline: 1.8809x; 1.8809x over previous
//
#include <hip/hip_runtime.h>
#include <hip/hip_bf16.h>
#include <math.h>

#define BB 64
#define NN 256
#define D_VIS 2048
#define D_LBL 512
#define HH 8
#define FF 256
#define DG 2048   // D_GAT = H*F
#define DE 512    // D_EMB
#define ALPHA 0.2f
#define ITILE 16
#define NEG_BIG -1.0e30f
#define KC 32
#define KSPLIT 256

using bf16 = __hip_bfloat16;
__device__ __forceinline__ float b2f(bf16 x) { return __bfloat162float(x); }

// ---------------- generic fp32 GEMM: C[r0:r0+64, c0:c0+64] += A[.,kz*256:+256] @ W[...]
// grid = (Ntiles, Mtiles, Ksplits); block 256. C must be pre-initialized (0 or bias).
__global__ void __launch_bounds__(256) k_gemm64(const float* __restrict__ A, int lda,
                                                const float* __restrict__ W, int ldw,
                                                float* __restrict__ C, int ldc) {
    __shared__ float As[KC][68]; // [k][row], pad 4 keeps float4 16B alignment
    __shared__ float Ws[KC][68]; // [k][col]
    const int t = threadIdx.x;
    const int c0 = blockIdx.x * 64;
    const int r0 = blockIdx.y * 64;
    const int kbase0 = blockIdx.z * KSPLIT;
    const int tr = t >> 4, tc = t & 15;
    float acc[4][4] = {};
    for (int ch = 0; ch < KSPLIT / KC; ++ch) {
        const int kb = kbase0 + ch * KC;
#pragma unroll
        for (int i = 0; i < 8; ++i) {
            const int e = t + 256 * i;
            const int kk = e & 31, r = e >> 5;
            As[kk][r] = A[(size_t)(r0 + r) * lda + kb + kk];
        }
#pragma unroll
        for (int i = 0; i < 8; ++i) {
            const int e = t + 256 * i;
            const int c = e & 63, kk = e >> 6;
            Ws[kk][c] = W[(size_t)(kb + kk) * ldw + c0 + c];
        }
        __syncthreads();
#pragma unroll 8
        for (int kk = 0; kk < KC; ++kk) {
            const float4 av = *(const float4*)&As[kk][4 * tr]; // 16-way broadcast
            const float4 wv = *(const float4*)&Ws[kk][4 * tc];
            const float aa[4] = {av.x, av.y, av.z, av.w};
            const float ww[4] = {wv.x, wv.y, wv.z, wv.w};
#pragma unroll
            for (int a = 0; a < 4; ++a)
#pragma unroll
                for (int k = 0; k < 4; ++k)
                    acc[a][k] = fmaf(aa[a], ww[k], acc[a][k]);
        }
        __syncthreads();
    }
#pragma unroll
    for (int a = 0; a < 4; ++a)
#pragma unroll
        for (int k = 0; k < 4; ++k)
            atomicAdd(&C[(size_t)(r0 + 4 * tr + a) * ldc + c0 + 4 * tc + k], acc[a][k]);
}

// ---------------- init out with bias (fc accumulates into it)
__global__ void __launch_bounds__(256) k_bias(const float* __restrict__ fcb,
                                              float* __restrict__ out) {
    const int i = blockIdx.x * 256 + threadIdx.x; // BB*DE = 32768
    out[i] = fcb[i & (DE - 1)];
}

// ---------------- K3: per-row head projections  src[n,h] = sum_f M[n,h*F+f]*a_src[h,f]
__global__ void k_proj(const float* __restrict__ M,
                       const float* __restrict__ a_src, const float* __restrict__ a_dst,
                       float* __restrict__ src, float* __restrict__ dst) {
    const int n = blockIdx.x;
    const int lane = threadIdx.x; // block = 64 (one wave)
    const float* mr = M + (size_t)n * DG;
    for (int h = 0; h < HH; ++h) {
        float s = 0.f, d_ = 0.f;
#pragma unroll
        for (int k = 0; k < 4; ++k) {
            const int f = lane + 64 * k;
            const float v = mr[h * FF + f];
            s  = fmaf(v, a_src[h * FF + f], s);
            d_ = fmaf(v, a_dst[h * FF + f], d_);
        }
#pragma unroll
        for (int off = 32; off; off >>= 1) {
            s  += __shfl_down(s, off);
            d_ += __shfl_down(d_, off);
        }
        if (lane == 0) { src[n * HH + h] = s; dst[n * HH + h] = d_; }
    }
}

// ---------------- K4: fused attention: softmax(mask(leaky(e))) @ WhL + WhV, ELU, -> bf16 out
__global__ void __launch_bounds__(256) k_gat(const float* __restrict__ WhL,
                                             const float* __restrict__ WhV,
                                             const float* __restrict__ srcL,
                                             const float* __restrict__ dstL,
                                             const float* __restrict__ srcV,
                                             const float* __restrict__ dstV,
                                             const float* __restrict__ adj,
                                             bf16* __restrict__ outb) {
    const int bid = blockIdx.x;
    const int it = bid & 15;
    const int h  = (bid >> 4) & 7;
    const int b  = bid >> 7;
    const int i0 = it * ITILE;
    const int t = threadIdx.x;

    __shared__ __align__(16) float Pt[NN][ITILE + 4];
    __shared__ float sl[ITILE];
    __shared__ float dl[NN];

    if (t < ITILE) sl[t] = srcL[(i0 + t) * HH + h];
    dl[t] = dstL[t * HH + h];
    const float c = srcV[b * HH + h] + dstV[b * HH + h];
    __syncthreads();

    const int row = t >> 4;
    const int sub = t & 15;
    const int i = i0 + row;
    float sc[16];
    float m = NEG_BIG;
#pragma unroll
    for (int jj = 0; jj < 16; ++jj) {
        const int j = sub + 16 * jj;
        float e = c + sl[row] + dl[j];
        e = e > 0.f ? e : ALPHA * e;
        const bool valid = adj[i * NN + j] > 0.f;
        const float s = valid ? e : NEG_BIG;
        sc[jj] = s;
        m = fmaxf(m, s);
    }
#pragma unroll
    for (int off = 1; off < 16; off <<= 1) m = fmaxf(m, __shfl_xor(m, off));
    float sum = 0.f;
#pragma unroll
    for (int jj = 0; jj < 16; ++jj) {
        const float p = __expf(sc[jj] - m);
        sc[jj] = p;
        sum += p;
    }
#pragma unroll
    for (int off = 1; off < 16; off <<= 1) sum += __shfl_xor(sum, off);
    const float inv = 1.0f / sum;
#pragma unroll
    for (int jj = 0; jj < 16; ++jj) {
        const int j = sub + 16 * jj;
        Pt[j][row] = sc[jj] * inv;
    }
    __syncthreads();

    const int fi = t & 63;
    const int ig = t >> 6;
    const float* wbase = WhL + h * FF + 4 * fi;
    float acc[4][4];
#pragma unroll
    for (int a = 0; a < 4; ++a)
#pragma unroll
        for (int k = 0; k < 4; ++k) acc[a][k] = 0.f;
    for (int j = 0; j < NN; ++j) {
        const float4 w = *(const float4*)(wbase + (size_t)j * DG);
        const float4 p = *(const float4*)(&Pt[j][4 * ig]);
        float pa[4] = {p.x, p.y, p.z, p.w};
        float wa[4] = {w.x, w.y, w.z, w.w};
#pragma unroll
        for (int a = 0; a < 4; ++a)
#pragma unroll
            for (int k = 0; k < 4; ++k) acc[a][k] = fmaf(pa[a], wa[k], acc[a][k]);
    }
    const float4 wv = *(const float4*)(WhV + (size_t)b * DG + h * FF + 4 * fi);
    const float wva[4] = {wv.x, wv.y, wv.z, wv.w};
#pragma unroll
    for (int a = 0; a < 4; ++a) {
        const int gi = i0 + 4 * ig + a;
        bf16 pk[4];
#pragma unroll
        for (int k = 0; k < 4; ++k) {
            float x = acc[a][k] + wva[k];
            x = x > 0.f ? x : (expf(x) - 1.0f);
            pk[k] = __float2bfloat16(x);
        }
        __builtin_memcpy(outb + ((size_t)(b * NN + gi)) * DG + h * FF + 4 * fi, pk, 8);
    }
}

// ---------------- K5: pooling scores s[b,n] = <out[b,n,:], pool_q>
__global__ void __launch_bounds__(256) k_pscore(const bf16* __restrict__ outb,
                                                const float* __restrict__ pool_q,
                                                float* __restrict__ ps) {
    const int bn = blockIdx.x;
    const bf16* rowp = outb + (size_t)bn * DG;
    const int t = threadIdx.x;
    float s = 0.f;
#pragma unroll
    for (int k = 0; k < 8; ++k) {
        const int d = t + 256 * k;
        s = fmaf(b2f(rowp[d]), pool_q[d], s);
    }
    __shared__ float red[4];
#pragma unroll
    for (int off = 32; off; off >>= 1) s += __shfl_down(s, off);
    if ((t & 63) == 0) red[t >> 6] = s;
    __syncthreads();
    if (t == 0) ps[bn] = red[0] + red[1] + red[2] + red[3];
}

// ---------------- K5b: softmax over n (in place)
__global__ void __launch_bounds__(256) k_psoftmax(float* __restrict__ ps) {
    const int b = blockIdx.x, t = threadIdx.x;
    const float v = ps[b * NN + t];
    __shared__ float redm[4];
    __shared__ float reds[4];
    float m = v;
#pragma unroll
    for (int off = 32; off; off >>= 1) m = fmaxf(m, __shfl_xor(m, off));
    if ((t & 63) == 0) redm[t >> 6] = m;
    __syncthreads();
    m = fmaxf(fmaxf(redm[0], redm[1]), fmaxf(redm[2], redm[3]));
    const float e = expf(v - m);
    float s = e;
#pragma unroll
    for (int off = 32; off; off >>= 1) s += __shfl_xor(s, off);
    if ((t & 63) == 0) reds[t >> 6] = s;
    __syncthreads();
    s = reds[0] + reds[1] + reds[2] + reds[3];
    ps[b * NN + t] = e / s;
}

// ---------------- K6: pooled[b, dtile] = sum_n pw[b,n] * out[b,n,dtile]  (grid 8 x 64)
__global__ void __launch_bounds__(256) k_pool(const bf16* __restrict__ outb,
                                              const float* __restrict__ pw,
                                              float* __restrict__ pooled) {
    const int dt = blockIdx.x;  // 0..7
    const int b  = blockIdx.y;  // 0..63
    const int t  = threadIdx.x;
    const int d  = dt * 256 + t;
    __shared__ float w[NN];
    w[t] = pw[b * NN + t];
    __syncthreads();
    float acc = 0.f;
    const bf16* base = outb + (size_t)b * NN * DG + d;
    for (int n = 0; n < NN; ++n)
        acc = fmaf(w[n], b2f(base[(size_t)n * DG]), acc);
    pooled[(size_t)b * DG + d] = acc;
}

extern "C" void kernel_launch(void* const* d_in, const int* in_sizes, int n_in,
                              void* d_out, int out_size, void* d_ws, size_t ws_size,
                              hipStream_t stream) {
    (void)in_sizes; (void)n_in; (void)out_size; (void)ws_size;
    const float* visual = (const float*)d_in[0];
    const float* labels = (const float*)d_in[1];
    const float* adj    = (const float*)d_in[2];
    const float* Wg     = (const float*)d_in[3];
    const float* a_src  = (const float*)d_in[4];
    const float* a_dst  = (const float*)d_in[5];
    const float* pool_q = (const float*)d_in[6];
    const float* fcW    = (const float*)d_in[7];
    const float* fcb    = (const float*)d_in[8];
    float* out = (float*)d_out;

    float* ws_f   = (float*)d_ws;
    float* WhL    = ws_f;                  // 256*2048
    float* WhV    = WhL + NN * DG;         // 64*2048
    float* srcL   = WhV + BB * DG;         // 256*8
    float* dstL   = srcL + NN * HH;        // 256*8
    float* srcV   = dstL + NN * HH;        // 64*8
    float* dstV   = srcV + BB * HH;        // 64*8
    float* ps     = dstV + BB * HH;        // 64*256
    float* pooled = ps + BB * NN;          // 64*2048
    bf16*  outb   = (bf16*)(pooled + BB * DG); // 64*256*2048 bf16

    // zero accumulation targets (harness poisons ws with 0xAA)
    hipMemsetAsync(WhL, 0, (size_t)NN * DG * sizeof(float), stream);
    hipMemsetAsync(WhV, 0, (size_t)BB * DG * sizeof(float), stream);
    k_bias<<<BB * DE / 256, 256, 0, stream>>>(fcb, out);

    // WhL = labels(256x512) @ Wg[0:512]:   grid (32 coltiles, 4 rowtiles, 2 ksplits)
    k_gemm64<<<dim3(DG / 64, NN / 64, D_LBL / KSPLIT), 256, 0, stream>>>(
        labels, D_LBL, Wg, DG, WhL, DG);
    // WhV = visual(64x2048) @ Wg[512:2560]: grid (32, 1, 8)
    k_gemm64<<<dim3(DG / 64, BB / 64, D_VIS / KSPLIT), 256, 0, stream>>>(
        visual, D_VIS, Wg + (size_t)D_LBL * DG, DG, WhV, DG);

    k_proj<<<NN, 64, 0, stream>>>(WhL, a_src, a_dst, srcL, dstL);
    k_proj<<<BB, 64, 0, stream>>>(WhV, a_src, a_dst, srcV, dstV);

    k_gat<<<BB * HH * 16, 256, 0, stream>>>(WhL, WhV, srcL, dstL, srcV, dstV, adj, outb);

    k_pscore<<<BB * NN, 256, 0, stream>>>(outb, pool_q, ps);
    k_psoftmax<<<BB, 256, 0, stream>>>(ps);
    k_pool<<<dim3(DG / 256, BB), 256, 0, stream>>>(outb, ps, pooled);

    // out = pooled(64x2048) @ fcW(2048x512) + fc_b: grid (8, 1, 8)
    k_gemm64<<<dim3(DE / 64, BB / 64, DG / KSPLIT), 256, 0, stream>>>(
        pooled, DG, fcW, DE, out, DE);
}

// Round 4
// 372.051 us; speedup vs baseline: 2.8525x; 1.5165x over previous
//
#include <hip/hip_runtime.h>
#include <hip/hip_bf16.h>
#include <math.h>

#define BB 64
#define NN 256
#define D_VIS 2048
#define D_LBL 512
#define HH 8
#define FF 256
#define DG 2048   // D_GAT = H*F
#define DE 512    // D_EMB
#define ALPHA 0.2f
#define NEG_BIG -1.0e30f
#define KC 32
#define KSPLIT 256
#define PPAD 8    // P row pad (bf16 elems): stride 264*2=528B -> 4-bank rotate

using bf16 = __hip_bfloat16;
using short8 = __attribute__((ext_vector_type(8))) short;
using f32x4  = __attribute__((ext_vector_type(4))) float;
__device__ __forceinline__ float b2f(bf16 x) { return __bfloat162float(x); }
__device__ __forceinline__ unsigned short f2bs(float x) {
    bf16 h = __float2bfloat16(x);
    unsigned short u;
    __builtin_memcpy(&u, &h, 2);
    return u;
}

// ---------------- generic fp32 GEMM: C[r0:+64, c0:+64] += A-tile @ W-tile (atomic)
__global__ void __launch_bounds__(256) k_gemm64(const float* __restrict__ A, int lda,
                                                const float* __restrict__ W, int ldw,
                                                float* __restrict__ C, int ldc) {
    __shared__ float As[KC][68];
    __shared__ float Ws[KC][68];
    const int t = threadIdx.x;
    const int c0 = blockIdx.x * 64;
    const int r0 = blockIdx.y * 64;
    const int kbase0 = blockIdx.z * KSPLIT;
    const int tr = t >> 4, tc = t & 15;
    float acc[4][4] = {};
    for (int ch = 0; ch < KSPLIT / KC; ++ch) {
        const int kb = kbase0 + ch * KC;
#pragma unroll
        for (int i = 0; i < 8; ++i) {
            const int e = t + 256 * i;
            const int kk = e & 31, r = e >> 5;
            As[kk][r] = A[(size_t)(r0 + r) * lda + kb + kk];
        }
#pragma unroll
        for (int i = 0; i < 8; ++i) {
            const int e = t + 256 * i;
            const int c = e & 63, kk = e >> 6;
            Ws[kk][c] = W[(size_t)(kb + kk) * ldw + c0 + c];
        }
        __syncthreads();
#pragma unroll 8
        for (int kk = 0; kk < KC; ++kk) {
            const float4 av = *(const float4*)&As[kk][4 * tr];
            const float4 wv = *(const float4*)&Ws[kk][4 * tc];
            const float aa[4] = {av.x, av.y, av.z, av.w};
            const float ww[4] = {wv.x, wv.y, wv.z, wv.w};
#pragma unroll
            for (int a = 0; a < 4; ++a)
#pragma unroll
                for (int k = 0; k < 4; ++k)
                    acc[a][k] = fmaf(aa[a], ww[k], acc[a][k]);
        }
        __syncthreads();
    }
#pragma unroll
    for (int a = 0; a < 4; ++a)
#pragma unroll
        for (int k = 0; k < 4; ++k)
            atomicAdd(&C[(size_t)(r0 + 4 * tr + a) * ldc + c0 + 4 * tc + k], acc[a][k]);
}

// ---------------- init out with bias
__global__ void __launch_bounds__(256) k_bias(const float* __restrict__ fcb,
                                              float* __restrict__ out) {
    const int i = blockIdx.x * 256 + threadIdx.x;
    out[i] = fcb[i & (DE - 1)];
}

// ---------------- pack WhL (fp32 [j=256][d=2048]) -> WhLbT (bf16 [d=2048][j=256])
__global__ void __launch_bounds__(256) k_packW(const float* __restrict__ WhL,
                                               unsigned short* __restrict__ WhLbT) {
    __shared__ float tile[64][65];
    const int t = threadIdx.x;
    const int d0 = blockIdx.x * 64;  // 0..31
    const int j0 = blockIdx.y * 64;  // 0..3
#pragma unroll
    for (int e = 0; e < 16; ++e) {
        const int idx = t + 256 * e;
        const int r = idx >> 6, c = idx & 63;
        tile[r][c] = WhL[(size_t)(j0 + r) * DG + d0 + c];
    }
    __syncthreads();
#pragma unroll
    for (int e = 0; e < 16; ++e) {
        const int idx = t + 256 * e;
        const int d = idx >> 6, j = idx & 63;
        WhLbT[(size_t)(d0 + d) * NN + j0 + j] = f2bs(tile[j][d]);
    }
}

// ---------------- K3: per-row head projections
__global__ void k_proj(const float* __restrict__ M,
                       const float* __restrict__ a_src, const float* __restrict__ a_dst,
                       float* __restrict__ src, float* __restrict__ dst) {
    const int n = blockIdx.x;
    const int lane = threadIdx.x; // 64
    const float* mr = M + (size_t)n * DG;
    for (int h = 0; h < HH; ++h) {
        float s = 0.f, d_ = 0.f;
#pragma unroll
        for (int k = 0; k < 4; ++k) {
            const int f = lane + 64 * k;
            const float v = mr[h * FF + f];
            s  = fmaf(v, a_src[h * FF + f], s);
            d_ = fmaf(v, a_dst[h * FF + f], d_);
        }
#pragma unroll
        for (int off = 32; off; off >>= 1) {
            s  += __shfl_down(s, off);
            d_ += __shfl_down(d_, off);
        }
        if (lane == 0) { src[n * HH + h] = s; dst[n * HH + h] = d_; }
    }
}

// ---------------- K4: MFMA GAT. grid = (b,h,it): 64*8*4 blocks, 256 thr (4 waves).
// Block computes out rows i0..i0+63 for head h, all 256 f-cols.
__global__ void __launch_bounds__(256) k_gat(const unsigned short* __restrict__ WhLbT,
                                             const float* __restrict__ WhV,
                                             const float* __restrict__ srcL,
                                             const float* __restrict__ dstL,
                                             const float* __restrict__ srcV,
                                             const float* __restrict__ dstV,
                                             const float* __restrict__ adj,
                                             bf16* __restrict__ outb) {
    const int bid = blockIdx.x;
    const int it = bid & 3;
    const int h  = (bid >> 2) & 7;
    const int b  = bid >> 5;
    const int i0 = it * 64;
    const int t = threadIdx.x;
    const int w = t >> 6;     // wave 0..3
    const int lane = t & 63;

    __shared__ __align__(16) unsigned short Pl[64][NN + PPAD]; // bf16 bits, 33 KB

    // ---- phase 1: softmax rows (wave w handles rows w*16..w*16+15)
    const float c = srcV[b * HH + h] + dstV[b * HH + h];
    float dlv[4];
#pragma unroll
    for (int q = 0; q < 4; ++q) dlv[q] = dstL[(lane + 64 * q) * HH + h];

    for (int r = 0; r < 16; ++r) {
        const int iloc = w * 16 + r;
        const int i = i0 + iloc;
        const float slr = srcL[i * HH + h];
        float sc[4];
        float m = NEG_BIG;
#pragma unroll
        for (int q = 0; q < 4; ++q) {
            const int j = lane + 64 * q;
            float e = c + slr + dlv[q];
            e = e > 0.f ? e : ALPHA * e;
            const float s = (adj[i * NN + j] > 0.f) ? e : NEG_BIG;
            sc[q] = s;
            m = fmaxf(m, s);
        }
#pragma unroll
        for (int off = 1; off < 64; off <<= 1) m = fmaxf(m, __shfl_xor(m, off));
        float sum = 0.f;
#pragma unroll
        for (int q = 0; q < 4; ++q) {
            const float p = __expf(sc[q] - m);
            sc[q] = p;
            sum += p;
        }
#pragma unroll
        for (int off = 1; off < 64; off <<= 1) sum += __shfl_xor(sum, off);
        const float inv = 1.0f / sum;
#pragma unroll
        for (int q = 0; q < 4; ++q)
            Pl[iloc][lane + 64 * q] = f2bs(sc[q] * inv);
    }
    __syncthreads();

    // ---- phase 2: out[i0+0:64, n0+0:64] = P @ W  via mfma 16x16x32 bf16
    const int n0 = w * 64;                 // wave's 64 f-cols
    const int l15 = lane & 15, quad = lane >> 4;
    f32x4 acc[4][4];
#pragma unroll
    for (int mi = 0; mi < 4; ++mi)
#pragma unroll
        for (int ni = 0; ni < 4; ++ni) acc[mi][ni] = (f32x4){0.f, 0.f, 0.f, 0.f};

    const unsigned short* wb = WhLbT + (size_t)(h * FF + n0 + l15) * NN + quad * 8;
#pragma unroll 2
    for (int kc = 0; kc < 8; ++kc) {
        short8 a[4], bfr[4];
#pragma unroll
        for (int mi = 0; mi < 4; ++mi)
            a[mi] = *(const short8*)&Pl[mi * 16 + l15][kc * 32 + quad * 8];
#pragma unroll
        for (int ni = 0; ni < 4; ++ni)
            bfr[ni] = *(const short8*)(wb + (size_t)(ni * 16) * NN + kc * 32);
#pragma unroll
        for (int mi = 0; mi < 4; ++mi)
#pragma unroll
            for (int ni = 0; ni < 4; ++ni)
                acc[mi][ni] = __builtin_amdgcn_mfma_f32_16x16x32_bf16(
                    a[mi], bfr[ni], acc[mi][ni], 0, 0, 0);
    }

    // ---- epilogue: +WhV, ELU, store bf16
    float wv[4];
#pragma unroll
    for (int ni = 0; ni < 4; ++ni)
        wv[ni] = WhV[(size_t)b * DG + h * FF + n0 + ni * 16 + l15];
#pragma unroll
    for (int mi = 0; mi < 4; ++mi) {
#pragma unroll
        for (int ni = 0; ni < 4; ++ni) {
            const int f = h * FF + n0 + ni * 16 + l15;
#pragma unroll
            for (int r = 0; r < 4; ++r) {
                const int i = i0 + mi * 16 + quad * 4 + r;
                float x = acc[mi][ni][r] + wv[ni];
                x = x > 0.f ? x : (__expf(x) - 1.0f);
                outb[((size_t)(b * NN + i)) * DG + f] = __float2bfloat16(x);
            }
        }
    }
}

// ---------------- K5: pooling scores
__global__ void __launch_bounds__(256) k_pscore(const bf16* __restrict__ outb,
                                                const float* __restrict__ pool_q,
                                                float* __restrict__ ps) {
    const int bn = blockIdx.x;
    const bf16* rowp = outb + (size_t)bn * DG;
    const int t = threadIdx.x;
    float s = 0.f;
#pragma unroll
    for (int k = 0; k < 8; ++k) {
        const int d = t + 256 * k;
        s = fmaf(b2f(rowp[d]), pool_q[d], s);
    }
    __shared__ float red[4];
#pragma unroll
    for (int off = 32; off; off >>= 1) s += __shfl_down(s, off);
    if ((t & 63) == 0) red[t >> 6] = s;
    __syncthreads();
    if (t == 0) ps[bn] = red[0] + red[1] + red[2] + red[3];
}

// ---------------- K5b: softmax over n
__global__ void __launch_bounds__(256) k_psoftmax(float* __restrict__ ps) {
    const int b = blockIdx.x, t = threadIdx.x;
    const float v = ps[b * NN + t];
    __shared__ float redm[4];
    __shared__ float reds[4];
    float m = v;
#pragma unroll
    for (int off = 32; off; off >>= 1) m = fmaxf(m, __shfl_xor(m, off));
    if ((t & 63) == 0) redm[t >> 6] = m;
    __syncthreads();
    m = fmaxf(fmaxf(redm[0], redm[1]), fmaxf(redm[2], redm[3]));
    const float e = expf(v - m);
    float s = e;
#pragma unroll
    for (int off = 32; off; off >>= 1) s += __shfl_xor(s, off);
    if ((t & 63) == 0) reds[t >> 6] = s;
    __syncthreads();
    s = reds[0] + reds[1] + reds[2] + reds[3];
    ps[b * NN + t] = e / s;
}

// ---------------- K6: pooled
__global__ void __launch_bounds__(256) k_pool(const bf16* __restrict__ outb,
                                              const float* __restrict__ pw,
                                              float* __restrict__ pooled) {
    const int dt = blockIdx.x;
    const int b  = blockIdx.y;
    const int t  = threadIdx.x;
    const int d  = dt * 256 + t;
    __shared__ float w[NN];
    w[t] = pw[b * NN + t];
    __syncthreads();
    float acc = 0.f;
    const bf16* base = outb + (size_t)b * NN * DG + d;
    for (int n = 0; n < NN; ++n)
        acc = fmaf(w[n], b2f(base[(size_t)n * DG]), acc);
    pooled[(size_t)b * DG + d] = acc;
}

extern "C" void kernel_launch(void* const* d_in, const int* in_sizes, int n_in,
                              void* d_out, int out_size, void* d_ws, size_t ws_size,
                              hipStream_t stream) {
    (void)in_sizes; (void)n_in; (void)out_size; (void)ws_size;
    const float* visual = (const float*)d_in[0];
    const float* labels = (const float*)d_in[1];
    const float* adj    = (const float*)d_in[2];
    const float* Wg     = (const float*)d_in[3];
    const float* a_src  = (const float*)d_in[4];
    const float* a_dst  = (const float*)d_in[5];
    const float* pool_q = (const float*)d_in[6];
    const float* fcW    = (const float*)d_in[7];
    const float* fcb    = (const float*)d_in[8];
    float* out = (float*)d_out;

    float* ws_f   = (float*)d_ws;
    float* WhL    = ws_f;                  // 256*2048
    float* WhV    = WhL + NN * DG;         // 64*2048
    float* srcL   = WhV + BB * DG;         // 256*8
    float* dstL   = srcL + NN * HH;        // 256*8
    float* srcV   = dstL + NN * HH;        // 64*8
    float* dstV   = srcV + BB * HH;        // 64*8
    float* ps     = dstV + BB * HH;        // 64*256
    float* pooled = ps + BB * NN;          // 64*2048
    bf16*  outb   = (bf16*)(pooled + BB * DG);        // 64*256*2048 bf16
    unsigned short* WhLbT = (unsigned short*)(outb + (size_t)BB * NN * DG); // 2048*256

    hipMemsetAsync(WhL, 0, (size_t)NN * DG * sizeof(float), stream);
    hipMemsetAsync(WhV, 0, (size_t)BB * DG * sizeof(float), stream);
    k_bias<<<BB * DE / 256, 256, 0, stream>>>(fcb, out);

    k_gemm64<<<dim3(DG / 64, NN / 64, D_LBL / KSPLIT), 256, 0, stream>>>(
        labels, D_LBL, Wg, DG, WhL, DG);
    k_gemm64<<<dim3(DG / 64, BB / 64, D_VIS / KSPLIT), 256, 0, stream>>>(
        visual, D_VIS, Wg + (size_t)D_LBL * DG, DG, WhV, DG);

    k_packW<<<dim3(DG / 64, NN / 64), 256, 0, stream>>>(WhL, WhLbT);
    k_proj<<<NN, 64, 0, stream>>>(WhL, a_src, a_dst, srcL, dstL);
    k_proj<<<BB, 64, 0, stream>>>(WhV, a_src, a_dst, srcV, dstV);

    k_gat<<<BB * HH * 4, 256, 0, stream>>>(WhLbT, WhV, srcL, dstL, srcV, dstV, adj, outb);

    k_pscore<<<BB * NN, 256, 0, stream>>>(outb, pool_q, ps);
    k_psoftmax<<<BB, 256, 0, stream>>>(ps);
    k_pool<<<dim3(DG / 256, BB), 256, 0, stream>>>(outb, ps, pooled);

    k_gemm64<<<dim3(DE / 64, BB / 64, DG / KSPLIT), 256, 0, stream>>>(
        pooled, DG, fcW, DE, out, DE);
}

// Round 6
// 221.448 us; speedup vs baseline: 4.7925x; 1.6801x over previous
//
#include <hip/hip_runtime.h>
#include <hip/hip_bf16.h>
#include <math.h>

#define BB 64
#define NN 256
#define D_VIS 2048
#define D_LBL 512
#define HH 8
#define FF 256
#define DG 2048   // D_GAT = H*F
#define DE 512    // D_EMB
#define ALPHA 0.2f
#define PSTRIDE 264  // Pl row stride in shorts (256 + 8 pad)

using bf16 = __hip_bfloat16;
using short8 = __attribute__((ext_vector_type(8))) short;
using f32x4  = __attribute__((ext_vector_type(4))) float;
__device__ __forceinline__ float b2f(bf16 x) { return __bfloat162float(x); }
__device__ __forceinline__ unsigned short f2bs(float x) {
    bf16 h = __float2bfloat16(x);
    unsigned short u;
    __builtin_memcpy(&u, &h, 2);
    return u;
}

// ---------------- unified bf16-MFMA GEMM: C[MxN] fp32 (+)= A[MxK] fp32 @ W[KxN] fp32
// grid (N/64, M/32, zsplit); block 256 (4 waves). Wave w owns cols n0+w*16..+16.
__global__ void __launch_bounds__(256) k_mgemm(const float* __restrict__ A, int lda,
                                               const float* __restrict__ W, int ldw,
                                               float* __restrict__ C, int ldc,
                                               int kSlice, int kIters, int useAtomic) {
    __shared__ unsigned short As[32][72]; // [m][k] bf16 bits
    __shared__ unsigned short Bs[64][72]; // [n][k] bf16 bits
    const int t = threadIdx.x;
    const int w = t >> 6;
    const int lane = t & 63;
    const int l15 = lane & 15, quad = lane >> 4;
    const int n0 = blockIdx.x * 64;
    const int m0 = blockIdx.y * 32;
    const int kb0 = blockIdx.z * kSlice;

    f32x4 acc[2];
    acc[0] = (f32x4){0.f, 0.f, 0.f, 0.f};
    acc[1] = (f32x4){0.f, 0.f, 0.f, 0.f};

    for (int kc = 0; kc < kIters; ++kc) {
        const int kb = kb0 + kc * 64;
#pragma unroll
        for (int p = 0; p < 2; ++p) {
            const int idx = t + 256 * p;
            const int r = idx >> 4, q4 = idx & 15;
            const float4 v = *(const float4*)(A + (size_t)(m0 + r) * lda + kb + 4 * q4);
            unsigned short s4[4] = {f2bs(v.x), f2bs(v.y), f2bs(v.z), f2bs(v.w)};
            __builtin_memcpy(&As[r][4 * q4], s4, 8);
        }
        {
            const int n = t & 63;
            float bv[16];
#pragma unroll
            for (int i = 0; i < 16; ++i)
                bv[i] = W[(size_t)(kb + w * 16 + i) * ldw + n0 + n];
            unsigned short s8[8];
#pragma unroll
            for (int i = 0; i < 8; ++i) s8[i] = f2bs(bv[i]);
            __builtin_memcpy(&Bs[n][w * 16], s8, 16);
#pragma unroll
            for (int i = 0; i < 8; ++i) s8[i] = f2bs(bv[8 + i]);
            __builtin_memcpy(&Bs[n][w * 16 + 8], s8, 16);
        }
        __syncthreads();
#pragma unroll
        for (int ks = 0; ks < 2; ++ks) {
            const short8 bf = *(const short8*)&Bs[w * 16 + l15][ks * 32 + quad * 8];
#pragma unroll
            for (int mi = 0; mi < 2; ++mi) {
                const short8 af = *(const short8*)&As[mi * 16 + l15][ks * 32 + quad * 8];
                acc[mi] = __builtin_amdgcn_mfma_f32_16x16x32_bf16(af, bf, acc[mi], 0, 0, 0);
            }
        }
        __syncthreads();
    }
    const int col = n0 + w * 16 + l15;
#pragma unroll
    for (int mi = 0; mi < 2; ++mi)
#pragma unroll
        for (int r = 0; r < 4; ++r) {
            const int row = m0 + mi * 16 + quad * 4 + r;
            if (useAtomic) atomicAdd(&C[(size_t)row * ldc + col], acc[mi][r]);
            else C[(size_t)row * ldc + col] = acc[mi][r];
        }
}

// ---------------- init out with bias
__global__ void __launch_bounds__(256) k_bias(const float* __restrict__ fcb,
                                              float* __restrict__ out) {
    const int i = blockIdx.x * 256 + threadIdx.x;
    out[i] = fcb[i & (DE - 1)];
}

// ---------------- pack WhL (fp32 [j][d]) -> WhLbT (bf16 [d][j])
__global__ void __launch_bounds__(256) k_packW(const float* __restrict__ WhL,
                                               unsigned short* __restrict__ WhLbT) {
    __shared__ float tile[64][65];
    const int t = threadIdx.x;
    const int d0 = blockIdx.x * 64;
    const int j0 = blockIdx.y * 64;
#pragma unroll
    for (int e = 0; e < 16; ++e) {
        const int idx = t + 256 * e;
        const int r = idx >> 6, c = idx & 63;
        tile[r][c] = WhL[(size_t)(j0 + r) * DG + d0 + c];
    }
    __syncthreads();
#pragma unroll
    for (int e = 0; e < 16; ++e) {
        const int idx = t + 256 * e;
        const int d = idx >> 6, j = idx & 63;
        WhLbT[(size_t)(d0 + d) * NN + j0 + j] = f2bs(tile[j][d]);
    }
}

// ---------------- per-row head projections
__global__ void k_proj(const float* __restrict__ M,
                       const float* __restrict__ a_src, const float* __restrict__ a_dst,
                       float* __restrict__ src, float* __restrict__ dst) {
    const int n = blockIdx.x;
    const int lane = threadIdx.x; // 64
    const float* mr = M + (size_t)n * DG;
    for (int h = 0; h < HH; ++h) {
        float s = 0.f, d_ = 0.f;
#pragma unroll
        for (int k = 0; k < 4; ++k) {
            const int f = lane + 64 * k;
            const float v = mr[h * FF + f];
            s  = fmaf(v, a_src[h * FF + f], s);
            d_ = fmaf(v, a_dst[h * FF + f], d_);
        }
#pragma unroll
        for (int off = 32; off; off >>= 1) {
            s  += __shfl_down(s, off);
            d_ += __shfl_down(d_, off);
        }
        if (lane == 0) { src[n * HH + h] = s; dst[n * HH + h] = d_; }
    }
}

// ---------------- MFMA GAT, fused softmax + P@W + ELU + store + pool-score
// grid (b,h,it) = 64*8*4 blocks, 256 thr (4 waves). Block: rows i0..i0+63, head h.
__global__ void __launch_bounds__(256) k_gat(const unsigned short* __restrict__ WhLbT,
                                             const float* __restrict__ WhV,
                                             const float* __restrict__ srcL,
                                             const float* __restrict__ dstL,
                                             const float* __restrict__ srcV,
                                             const float* __restrict__ dstV,
                                             const float* __restrict__ adj,
                                             const float* __restrict__ pool_q,
                                             bf16* __restrict__ outb,
                                             float* __restrict__ ps) {
    const int bid = blockIdx.x;
    const int it = bid & 3;
    const int h  = (bid >> 2) & 7;
    const int b  = bid >> 5;
    const int i0 = it * 64;
    const int t = threadIdx.x;
    const int w = t >> 6;
    const int lane = t & 63;
    const int l15 = lane & 15, quad = lane >> 4;

    __shared__ __align__(16) unsigned short Pl[64][PSTRIDE]; // 33 KB
    __shared__ float dls[NN];
    __shared__ float sls[64];

    dls[t] = dstL[t * HH + h];
    if (t < 64) sls[t] = srcL[(i0 + t) * HH + h];
    const float c = srcV[b * HH + h] + dstV[b * HH + h];
    __syncthreads();

    // ---- phase 1: masked softmax (no max-sub: |e| bounded), 16-lane groups
    {
        const int g = lane >> 4, s = lane & 15;
        for (int rr = 0; rr < 4; ++rr) {
            const int iloc = w * 16 + rr * 4 + g;
            const int i = i0 + iloc;
            const float u = c + sls[iloc];
            float pr[16];
            float sum = 0.f;
#pragma unroll
            for (int jj = 0; jj < 8; ++jj) {
                const int j0 = 2 * s + 32 * jj;
                const float2 av = *(const float2*)(adj + (size_t)i * NN + j0);
                float x0 = u + dls[j0];
                float x1 = u + dls[j0 + 1];
                x0 = fmaxf(x0, ALPHA * x0);       // LeakyReLU
                x1 = fmaxf(x1, ALPHA * x1);
                const float p0 = av.x > 0.f ? __expf(x0) : 0.f;
                const float p1 = av.y > 0.f ? __expf(x1) : 0.f;
                pr[2 * jj] = p0; pr[2 * jj + 1] = p1;
                sum += p0 + p1;
            }
#pragma unroll
            for (int off = 1; off < 16; off <<= 1) sum += __shfl_xor(sum, off);
            const float inv = 1.0f / sum;
#pragma unroll
            for (int jj = 0; jj < 8; ++jj) {
                const unsigned int pk =
                    ((unsigned int)f2bs(pr[2 * jj + 1] * inv) << 16) |
                    f2bs(pr[2 * jj] * inv);          // <-- FIX: normalize by inv
                *(unsigned int*)&Pl[iloc][2 * s + 32 * jj] = pk;
            }
        }
    }
    __syncthreads();

    // ---- phase 2: out[i0:+64, w*64:+64] = P @ WhL (mfma 16x16x32 bf16)
    const int n0 = w * 64;
    f32x4 acc[4][4];
#pragma unroll
    for (int mi = 0; mi < 4; ++mi)
#pragma unroll
        for (int ni = 0; ni < 4; ++ni) acc[mi][ni] = (f32x4){0.f, 0.f, 0.f, 0.f};

    const unsigned short* wb = WhLbT + (size_t)(h * FF + n0 + l15) * NN + quad * 8;
#pragma unroll 2
    for (int kc = 0; kc < 8; ++kc) {
        short8 a[4], bfr[4];
#pragma unroll
        for (int mi = 0; mi < 4; ++mi)
            a[mi] = *(const short8*)&Pl[mi * 16 + l15][kc * 32 + quad * 8];
#pragma unroll
        for (int ni = 0; ni < 4; ++ni)
            bfr[ni] = *(const short8*)(wb + (size_t)(ni * 16) * NN + kc * 32);
#pragma unroll
        for (int mi = 0; mi < 4; ++mi)
#pragma unroll
            for (int ni = 0; ni < 4; ++ni)
                acc[mi][ni] = __builtin_amdgcn_mfma_f32_16x16x32_bf16(
                    a[mi], bfr[ni], acc[mi][ni], 0, 0, 0);
    }
    __syncthreads(); // all waves done reading Pl

    // ---- epilogue A: +WhV, ELU, bf16 -> Pl[row][f]
    float wv[4];
#pragma unroll
    for (int ni = 0; ni < 4; ++ni)
        wv[ni] = WhV[(size_t)b * DG + h * FF + n0 + ni * 16 + l15];
#pragma unroll
    for (int mi = 0; mi < 4; ++mi)
#pragma unroll
        for (int ni = 0; ni < 4; ++ni)
#pragma unroll
            for (int r = 0; r < 4; ++r) {
                float x = acc[mi][ni][r] + wv[ni];
                x = x > 0.f ? x : (__expf(x) - 1.0f); // ELU
                Pl[mi * 16 + quad * 4 + r][n0 + ni * 16 + l15] = f2bs(x);
            }
    __syncthreads();

    // ---- epilogue B: coalesced b128 stores + fused pool-score partial dot
    {
        const int r = t >> 2;        // 0..63
        const int cb = t & 3;        // 0..3
        const int f0 = cb * 64;
        const float* pq = pool_q + h * FF + f0;
        bf16* orow = outb + ((size_t)(b * NN + i0 + r)) * DG + h * FF + f0;
        float dot = 0.f;
#pragma unroll
        for (int i8 = 0; i8 < 8; ++i8) {
            const short8 v = *(const short8*)&Pl[r][f0 + 8 * i8];
            __builtin_memcpy(orow + 8 * i8, &v, 16);
            const float4 q0 = *(const float4*)(pq + 8 * i8);
            const float4 q1 = *(const float4*)(pq + 8 * i8 + 4);
            bf16 bb[8];
            __builtin_memcpy(bb, &v, 16);
            dot = fmaf(b2f(bb[0]), q0.x, dot);
            dot = fmaf(b2f(bb[1]), q0.y, dot);
            dot = fmaf(b2f(bb[2]), q0.z, dot);
            dot = fmaf(b2f(bb[3]), q0.w, dot);
            dot = fmaf(b2f(bb[4]), q1.x, dot);
            dot = fmaf(b2f(bb[5]), q1.y, dot);
            dot = fmaf(b2f(bb[6]), q1.z, dot);
            dot = fmaf(b2f(bb[7]), q1.w, dot);
        }
        dot += __shfl_xor(dot, 1);
        dot += __shfl_xor(dot, 2);
        if (cb == 0) atomicAdd(&ps[b * NN + i0 + r], dot);
    }
}

// ---------------- softmax over n (in place)
__global__ void __launch_bounds__(256) k_psoftmax(float* __restrict__ ps) {
    const int b = blockIdx.x, t = threadIdx.x;
    const float v = ps[b * NN + t];
    __shared__ float redm[4];
    __shared__ float reds[4];
    float m = v;
#pragma unroll
    for (int off = 32; off; off >>= 1) m = fmaxf(m, __shfl_xor(m, off));
    if ((t & 63) == 0) redm[t >> 6] = m;
    __syncthreads();
    m = fmaxf(fmaxf(redm[0], redm[1]), fmaxf(redm[2], redm[3]));
    const float e = expf(v - m);
    float s = e;
#pragma unroll
    for (int off = 32; off; off >>= 1) s += __shfl_xor(s, off);
    if ((t & 63) == 0) reds[t >> 6] = s;
    __syncthreads();
    s = reds[0] + reds[1] + reds[2] + reds[3];
    ps[b * NN + t] = e / s;
}

// ---------------- pooled[b,d] = sum_n pw[b,n] * out[b,n,d]
__global__ void __launch_bounds__(256) k_pool(const bf16* __restrict__ outb,
                                              const float* __restrict__ pw,
                                              float* __restrict__ pooled) {
    const int dt = blockIdx.x;
    const int b  = blockIdx.y;
    const int t  = threadIdx.x;
    const int d  = dt * 256 + t;
    __shared__ float wsm[NN];
    wsm[t] = pw[b * NN + t];
    __syncthreads();
    float acc = 0.f;
    const bf16* base = outb + (size_t)b * NN * DG + d;
    for (int n = 0; n < NN; ++n)
        acc = fmaf(wsm[n], b2f(base[(size_t)n * DG]), acc);
    pooled[(size_t)b * DG + d] = acc;
}

extern "C" void kernel_launch(void* const* d_in, const int* in_sizes, int n_in,
                              void* d_out, int out_size, void* d_ws, size_t ws_size,
                              hipStream_t stream) {
    (void)in_sizes; (void)n_in; (void)out_size; (void)ws_size;
    const float* visual = (const float*)d_in[0];
    const float* labels = (const float*)d_in[1];
    const float* adj    = (const float*)d_in[2];
    const float* Wg     = (const float*)d_in[3];
    const float* a_src  = (const float*)d_in[4];
    const float* a_dst  = (const float*)d_in[5];
    const float* pool_q = (const float*)d_in[6];
    const float* fcW    = (const float*)d_in[7];
    const float* fcb    = (const float*)d_in[8];
    float* out = (float*)d_out;

    float* ws_f   = (float*)d_ws;
    float* WhL    = ws_f;                  // 256*2048
    float* WhV    = WhL + NN * DG;         // 64*2048
    float* srcL   = WhV + BB * DG;         // 256*8
    float* dstL   = srcL + NN * HH;        // 256*8
    float* srcV   = dstL + NN * HH;        // 64*8
    float* dstV   = srcV + BB * HH;        // 64*8
    float* ps     = dstV + BB * HH;        // 64*256
    float* pooled = ps + BB * NN;          // 64*2048
    bf16*  outb   = (bf16*)(pooled + BB * DG);        // 64*256*2048 bf16
    unsigned short* WhLbT = (unsigned short*)(outb + (size_t)BB * NN * DG); // 2048*256

    hipMemsetAsync(WhV, 0, (size_t)BB * DG * sizeof(float), stream);
    hipMemsetAsync(ps, 0, (size_t)BB * NN * sizeof(float), stream);
    k_bias<<<BB * DE / 256, 256, 0, stream>>>(fcb, out);

    // WhL = labels(256x512) @ Wg[0:512]:  grid (32, 8, 1), full-K direct store
    k_mgemm<<<dim3(DG / 64, NN / 32, 1), 256, 0, stream>>>(
        labels, D_LBL, Wg, DG, WhL, DG, D_LBL, D_LBL / 64, 0);
    // WhV = visual(64x2048) @ Wg[512:]:   grid (32, 2, 4), ksplit atomic
    k_mgemm<<<dim3(DG / 64, BB / 32, 4), 256, 0, stream>>>(
        visual, D_VIS, Wg + (size_t)D_LBL * DG, DG, WhV, DG, 512, 8, 1);

    k_packW<<<dim3(DG / 64, NN / 64), 256, 0, stream>>>(WhL, WhLbT);
    k_proj<<<NN, 64, 0, stream>>>(WhL, a_src, a_dst, srcL, dstL);
    k_proj<<<BB, 64, 0, stream>>>(WhV, a_src, a_dst, srcV, dstV);

    k_gat<<<BB * HH * 4, 256, 0, stream>>>(WhLbT, WhV, srcL, dstL, srcV, dstV,
                                           adj, pool_q, outb, ps);

    k_psoftmax<<<BB, 256, 0, stream>>>(ps);
    k_pool<<<dim3(DG / 256, BB), 256, 0, stream>>>(outb, ps, pooled);

    // out = pooled @ fcW + bias: grid (8, 2, 8), ksplit atomic into bias-init out
    k_mgemm<<<dim3(DE / 64, BB / 32, 8), 256, 0, stream>>>(
        pooled, DG, fcW, DE, out, DE, 256, 4, 1);
}